// Round 19
// baseline (357.748 us; speedup 1.0000x reference)
//
#include <hip/hip_runtime.h>
#include <stdint.h>
#include <math.h>

#define DEV static __device__ __forceinline__

typedef __attribute__((ext_vector_type(8))) short short8;
typedef __attribute__((ext_vector_type(4))) short short4v;
typedef __attribute__((ext_vector_type(4))) float f32x4;

#define B_ 4
#define T_ 2048
#define H_ 16
#define KVH_ 4
#define HD_ 128
#define DIM_ 2048
#define KVD_ 512
#define BT_ (B_ * T_)
#define KVS_ 1024   // fused KV row stride (K cols 0..511, V cols 512..1023)

DEV float bf2f(unsigned short h) {
  union { uint32_t u; float f; } v; v.u = ((uint32_t)h) << 16; return v.f;
}
DEV unsigned short f2bf(float f) {
  uint32_t u = __builtin_bit_cast(uint32_t, f);
  u += 0x7fffu + ((u >> 16) & 1u);   // round-to-nearest-even
  return (unsigned short)(u >> 16);
}
DEV void gll16(const void* g, void* l) {
  __builtin_amdgcn_global_load_lds(
      (const __attribute__((address_space(1))) unsigned int*)g,
      (__attribute__((address_space(3))) unsigned int*)l, 16, 0, 0);
}

#if __has_builtin(__builtin_amdgcn_exp2f)
#define EXP2F(x) __builtin_amdgcn_exp2f(x)
#else
#define EXP2F(x) exp2f(x)
#endif

// pack 4 fp32 -> 4 bf16 (RNE) via v_cvt_pk_bf16_f32
DEV short4v pack4(float a, float b, float c, float d) {
  union { uint32_t u[2]; short4v s; } r;
  asm("v_cvt_pk_bf16_f32 %0, %1, %2" : "=v"(r.u[0]) : "v"(a), "v"(b));
  asm("v_cvt_pk_bf16_f32 %0, %1, %2" : "=v"(r.u[1]) : "v"(c), "v"(d));
  return r.s;
}

#if __has_builtin(__builtin_amdgcn_mfma_f32_16x16x16bf16_1k)
#define MFMA16(A, Bo, C) __builtin_amdgcn_mfma_f32_16x16x16bf16_1k((A), (Bo), (C), 0, 0, 0)
#else
DEV f32x4 mfma16_asm(short4v a, short4v b, f32x4 c) {
  asm volatile("v_mfma_f32_16x16x16_bf16 %0, %1, %2, %0" : "+v"(c) : "v"(a), "v"(b));
  return c;
}
#define MFMA16(A, Bo, C) mfma16_asm((A), (Bo), (C))
#endif

// compiler-level + scheduler-level fence, then HW barrier (no vmcnt drain)
DEV void block_bar() {
  __builtin_amdgcn_sched_barrier(0);
  asm volatile("" ::: "memory");
  __builtin_amdgcn_s_barrier();
  asm volatile("" ::: "memory");
  __builtin_amdgcn_sched_barrier(0);
}

// ---------------- prep: fp32->bf16 convert of x + all 4 weight transposes ----------------
DEV void tr32(const float* __restrict__ W, unsigned short* __restrict__ Wt,
              int R, int C, int bx, int by, int tid) {
  __shared__ float t[32][33];
  int c0 = bx * 32, r0 = by * 32;
  int col = tid & 31;
  int rr = (tid >> 5) * 4;
#pragma unroll
  for (int i = 0; i < 4; ++i)
    t[rr + i][col] = W[(size_t)(r0 + rr + i) * C + c0 + col];
  __syncthreads();
#pragma unroll
  for (int i = 0; i < 4; ++i)
    Wt[(size_t)(c0 + rr + i) * R + r0 + col] = f2bf(t[col][rr + i]);
}

__global__ __launch_bounds__(256) void prep_kernel(
    const float* __restrict__ x, const float* __restrict__ Wq,
    const float* __restrict__ Wk, const float* __restrict__ Wv,
    const float* __restrict__ Wo, unsigned short* __restrict__ xb,
    unsigned short* __restrict__ Wall, unsigned short* __restrict__ Wot) {
  int id = blockIdx.x, tid = threadIdx.x;
  if (id < 8192) {
    size_t idx = (size_t)id * 2048 + tid * 8;
    float4 a = *(const float4*)(x + idx);
    float4 b = *(const float4*)(x + idx + 4);
    short8 o;
    o[0] = (short)f2bf(a.x); o[1] = (short)f2bf(a.y);
    o[2] = (short)f2bf(a.z); o[3] = (short)f2bf(a.w);
    o[4] = (short)f2bf(b.x); o[5] = (short)f2bf(b.y);
    o[6] = (short)f2bf(b.z); o[7] = (short)f2bf(b.w);
    *(short8*)(xb + idx) = o;
  } else if (id < 12288) {
    int t = id - 8192;
    tr32(Wq, Wall, DIM_, DIM_, t & 63, t >> 6, tid);
  } else if (id < 13312) {
    int t = id - 12288;
    tr32(Wk, Wall + (size_t)2048 * DIM_, DIM_, KVD_, t & 15, t >> 4, tid);
  } else if (id < 14336) {
    int t = id - 13312;
    tr32(Wv, Wall + (size_t)2560 * DIM_, DIM_, KVD_, t & 15, t >> 4, tid);
  } else {
    int t = id - 14336;
    tr32(Wo, Wot, DIM_, DIM_, t & 63, t >> 6, tid);
  }
}

// ---------------- RoPE in-place (bf16); one wave per head-row ----------------
__global__ __launch_bounds__(256) void rope_kernel(unsigned short* q,
                                                   unsigned short* kv) {
  int wid = blockIdx.x * 4 + (threadIdx.x >> 6);
  int lane = threadIdx.x & 63;
  const int NQ = B_ * T_ * H_;
  unsigned short* ptr;
  int t;
  if (wid < NQ) {
    int bt = wid >> 4, h = wid & (H_ - 1);
    ptr = q + (size_t)bt * DIM_ + h * HD_;
    t = bt & (T_ - 1);
  } else {
    int id = wid - NQ;
    int bt = id >> 2, g = id & (KVH_ - 1);
    ptr = kv + (size_t)bt * KVS_ + g * HD_;
    t = bt & (T_ - 1);
  }
  float inv = __expf(-(float)lane * 0.14391157f);  // ln(10000)/64
  float ang = (float)t * inv;
  float s = sinf(ang), c = cosf(ang);
  uint32_t zz = *(const uint32_t*)(ptr + lane * 2);
  float z1 = bf2f((unsigned short)(zz & 0xffff));
  float z2 = bf2f((unsigned short)(zz >> 16));
  unsigned short o1 = f2bf(z1 * c - z2 * s);
  unsigned short o2 = f2bf(z1 * s + z2 * c);
  ptr[lane] = o1;
  ptr[64 + lane] = o2;
}

// ---------------- GEMM 128² (m97 structure) — KV projection ----------------
__global__ __launch_bounds__(256) void gemm_bt(
    const unsigned short* __restrict__ A, const unsigned short* __restrict__ Bt,
    unsigned short* __restrict__ Cout, int M, int N, int K) {
  __shared__ unsigned short As[128 * 32];
  __shared__ unsigned short Bs[128 * 32];
  int m0 = blockIdx.y * 128, n0 = blockIdx.x * 128;
  int tid = threadIdx.x, w = tid >> 6, l = tid & 63;
  int wr = w >> 1, wc = w & 1;
  int l15 = l & 15, l4 = l >> 4;
  f32x4 acc[4][4] = {};
  for (int k0 = 0; k0 < K; k0 += 32) {
    __syncthreads();
#pragma unroll
    for (int i = 0; i < 2; ++i) {
      int u = i * 256 + w * 64 + l;
      int row = u >> 2, kc = u & 3;
      gll16(A + (size_t)(m0 + row) * K + k0 + kc * 8, As + (size_t)u * 8);
      gll16(Bt + (size_t)(n0 + row) * K + k0 + kc * 8, Bs + (size_t)u * 8);
    }
    __syncthreads();
    short8 a[4], b[4];
#pragma unroll
    for (int mb = 0; mb < 4; ++mb)
      a[mb] = *(const short8*)(As + ((wr * 64 + mb * 16 + l15) * 4 + l4) * 8);
#pragma unroll
    for (int nb = 0; nb < 4; ++nb)
      b[nb] = *(const short8*)(Bs + ((wc * 64 + nb * 16 + l15) * 4 + l4) * 8);
#pragma unroll
    for (int mb = 0; mb < 4; ++mb)
#pragma unroll
      for (int nb = 0; nb < 4; ++nb)
        acc[mb][nb] =
            __builtin_amdgcn_mfma_f32_16x16x32_bf16(a[mb], b[nb], acc[mb][nb], 0, 0, 0);
  }
#pragma unroll
  for (int mb = 0; mb < 4; ++mb)
#pragma unroll
    for (int nb = 0; nb < 4; ++nb)
#pragma unroll
      for (int r = 0; r < 4; ++r) {
        size_t off = (size_t)(m0 + wr * 64 + mb * 16 + l4 * 4 + r) * N +
                     n0 + wc * 64 + nb * 16 + l15;
        Cout[off] = f2bf(acc[mb][nb][r]);
      }
}

// ---------------- GEMM 256² deep-pipeline core (R13-proven two-phase) ----------------
#define GEMM256_BODY(A_, Bt_, K_, NX_)                                        \
  __shared__ unsigned short As[4][256 * 32];                                  \
  __shared__ unsigned short Bs[4][256 * 32];                                  \
  int tid = threadIdx.x, w = tid >> 6, l = tid & 63;                          \
  int wm = w >> 2, wn = w & 3;                                                \
  int l15 = l & 15, l4 = l >> 4;                                              \
  int cpx = (int)gridDim.x >> 3;                                              \
  int id = ((int)blockIdx.x & 7) * cpx + ((int)blockIdx.x >> 3);              \
  int bx = id % (NX_), by = id / (NX_);                                       \
  int m0 = by * 256, n0 = bx * 256;                                           \
  int nt = (K_) >> 5;                                                         \
  int u0 = tid * 16;                                                          \
  int ba0 = u0 ^ (((u0 >> 7) & 3) << 4);                                      \
  int r0 = ba0 >> 6;                                                          \
  int c0 = (ba0 & 63) >> 1;                                                   \
  f32x4 acc[8][4] = {};                                                       \
  _Pragma("unroll") for (int tt = 0; tt < 3; ++tt) {                          \
    const unsigned short* a0 = (A_) + (size_t)(m0 + r0) * (K_) + tt * 32 + c0;\
    gll16(a0, &As[tt][tid * 8]);                                              \
    gll16(a0 + (size_t)128 * (K_), &As[tt][4096 + tid * 8]);                  \
    const unsigned short* b0 = (Bt_) + (size_t)(n0 + r0) * (K_) + tt * 32 + c0;\
    gll16(b0, &Bs[tt][tid * 8]);                                              \
    gll16(b0 + (size_t)128 * (K_), &Bs[tt][4096 + tid * 8]);                  \
  }                                                                           \
  asm volatile("s_waitcnt vmcnt(8)" ::: "memory");                            \
  block_bar();                                                                \
  _Pragma("unroll 4") for (int t = 0; t < nt; ++t) {                          \
    int buf = t & 3;                                                          \
    int pf = t + 3;                                                           \
    bool dopf = pf < nt;                                                      \
    int pbuf = pf & 3;                                                        \
    if (dopf) {                                                               \
      const unsigned short* a0 = (A_) + (size_t)(m0 + r0) * (K_) + pf * 32 + c0;\
      gll16(a0, &As[pbuf][tid * 8]);                                          \
      gll16(a0 + (size_t)128 * (K_), &As[pbuf][4096 + tid * 8]);              \
    }                                                                         \
    short8 bfr[4], afr[4];                                                    \
    _Pragma("unroll") for (int nf = 0; nf < 4; ++nf) {                        \
      int row = wn * 64 + nf * 16 + l15;                                      \
      bfr[nf] = *(const short8*)(&Bs[buf][row * 32 + ((l4 ^ ((row >> 1) & 3)) << 3)]);\
    }                                                                         \
    _Pragma("unroll") for (int mf = 0; mf < 4; ++mf) {                        \
      int row = wm * 128 + mf * 16 + l15;                                     \
      afr[mf] = *(const short8*)(&As[buf][row * 32 + ((l4 ^ ((row >> 1) & 3)) << 3)]);\
    }                                                                         \
    asm volatile("s_waitcnt lgkmcnt(0)" ::: "memory");                        \
    __builtin_amdgcn_sched_barrier(0);                                        \
    __builtin_amdgcn_s_setprio(1);                                            \
    _Pragma("unroll") for (int mf = 0; mf < 4; ++mf)                          \
      _Pragma("unroll") for (int nf = 0; nf < 4; ++nf)                        \
        acc[mf][nf] = __builtin_amdgcn_mfma_f32_16x16x32_bf16(afr[mf], bfr[nf], acc[mf][nf], 0, 0, 0);\
    __builtin_amdgcn_s_setprio(0);                                            \
    block_bar();                                                              \
    if (dopf) {                                                               \
      const unsigned short* b0 = (Bt_) + (size_t)(n0 + r0) * (K_) + pf * 32 + c0;\
      gll16(b0, &Bs[pbuf][tid * 8]);                                          \
      gll16(b0 + (size_t)128 * (K_), &Bs[pbuf][4096 + tid * 8]);              \
    }                                                                         \
    short8 afr2[4];                                                           \
    _Pragma("unroll") for (int mf = 0; mf < 4; ++mf) {                        \
      int row = wm * 128 + 64 + mf * 16 + l15;                                \
      afr2[mf] = *(const short8*)(&As[buf][row * 32 + ((l4 ^ ((row >> 1) & 3)) << 3)]);\
    }                                                                         \
    asm volatile("s_waitcnt lgkmcnt(0)" ::: "memory");                        \
    __builtin_amdgcn_sched_barrier(0);                                        \
    __builtin_amdgcn_s_setprio(1);                                            \
    _Pragma("unroll") for (int mf = 0; mf < 4; ++mf)                          \
      _Pragma("unroll") for (int nf = 0; nf < 4; ++nf)                        \
        acc[4 + mf][nf] = __builtin_amdgcn_mfma_f32_16x16x32_bf16(afr2[mf], bfr[nf], acc[4 + mf][nf], 0, 0, 0);\
    __builtin_amdgcn_s_setprio(0);                                            \
    asm volatile("s_waitcnt vmcnt(8)" ::: "memory");                          \
    block_bar();                                                              \
  }

// ---------------- Q projection (bf16 out, SCALEQ folded) ----------------
__global__ __launch_bounds__(512, 2) void gemm256_q(
    const unsigned short* __restrict__ A, const unsigned short* __restrict__ Bt,
    unsigned short* __restrict__ Cq) {
  GEMM256_BODY(A, Bt, DIM_, 8)
  const float qs = 0.12752940f;   // (1/sqrt(128))*log2(e) for exp2-domain attn
#pragma unroll
  for (int mf = 0; mf < 8; ++mf)
#pragma unroll
    for (int nf = 0; nf < 4; ++nf)
#pragma unroll
      for (int r = 0; r < 4; ++r) {
        size_t off = (size_t)(m0 + wm * 128 + mf * 16 + l4 * 4 + r) * DIM_ +
                     n0 + wn * 64 + nf * 16 + l15;
        Cq[off] = f2bf(acc[mf][nf][r] * qs);
      }
}

// ---------------- O projection: fp32 out ----------------
__global__ __launch_bounds__(512, 2) void gemm256_out(
    const unsigned short* __restrict__ A, const unsigned short* __restrict__ Bt,
    float* __restrict__ Cout) {
  GEMM256_BODY(A, Bt, DIM_, 8)
#pragma unroll
  for (int mf = 0; mf < 8; ++mf)
#pragma unroll
    for (int nf = 0; nf < 4; ++nf)
#pragma unroll
      for (int r = 0; r < 4; ++r) {
        size_t off = (size_t)(m0 + wm * 128 + mf * 16 + l4 * 4 + r) * DIM_ +
                     n0 + wn * 64 + nf * 16 + l15;
        Cout[off] = acc[mf][nf][r];
      }
}

// ---------------- Flash attention v7 (proven best: 256 thr, QBLK=128) ----------------
__global__ __launch_bounds__(256, 2) void attn_kernel(
    const unsigned short* qws, const unsigned short* __restrict__ kvws,
    unsigned short* ows) {
  int bh = blockIdx.x;
  int qt = 15 - (int)blockIdx.y;      // LPT: longest first
  int b = bh >> 4, h = bh & 15, g = h >> 2;
  int tid = threadIdx.x, w = tid >> 6, l = tid & 63;
  int l15 = l & 15, l4 = l >> 4;

  __shared__ unsigned short Ks[64 * 128];     // 16 KB single
  __shared__ unsigned short Vt[2][128 * 64];  // 32 KB double (V^T, swizzled)

  const unsigned short* kbase = kvws + (size_t)(b * T_) * KVS_ + g * HD_;
  const unsigned short* vbase = kbase + KVD_;   // V cols at +512

  int q0 = qt * 128;
  int qw0 = q0 + w * 32;              // wave's first q row
  int qg = qw0 + l15;                 // lane's q row (qb adds 16)

  short8 qf[2][4];
#pragma unroll
  for (int qb = 0; qb < 2; ++qb) {
    const unsigned short* qrow =
        qws + (size_t)(b * T_ + qg + qb * 16) * DIM_ + h * HD_ + l4 * 8;
#pragma unroll
    for (int kc = 0; kc < 4; ++kc) qf[qb][kc] = *(const short8*)(qrow + kc * 32);
  }

  unsigned woff[8];
#pragma unroll
  for (int j = 0; j < 8; ++j)
    woff[j] = (unsigned)(j * 128 + (((l >> 3) ^ j) << 4) + ((l & 7) << 1));

  f32x4 o[2][8] = {};
  float m[2], ls[2];
  m[0] = m[1] = -INFINITY;
  ls[0] = ls[1] = 0.f;

#define STAGE_K(kt_)                                                     \
  {                                                                      \
    const unsigned short* kb = kbase + (size_t)(kt_) * 64 * KVS_;        \
    _Pragma("unroll") for (int i = 0; i < 4; ++i) {                      \
      int u = (i * 4 + w) * 64 + l;                                      \
      int row = u >> 4, c = u & 15;                                      \
      int kc = c ^ (row & 15);                                           \
      gll16(kb + (size_t)row * KVS_ + kc * 8, Ks + (size_t)u * 8);       \
    }                                                                    \
  }
#define VLOAD(kt_)                                                       \
  {                                                                      \
    const unsigned short* vrow = vbase + (size_t)((kt_) * 64 + l) * KVS_;\
    _Pragma("unroll") for (int i = 0; i < 4; ++i)                        \
      vg[i] = *(const short8*)(vrow + (w + i * 4) * 8);                  \
  }
#define VWRITE(buf_)                                                     \
  {                                                                      \
    char* vtb0 = (char*)Vt[buf_] + w * 1024;                             \
    _Pragma("unroll") for (int i = 0; i < 4; ++i)                        \
      _Pragma("unroll") for (int j = 0; j < 8; ++j)                      \
        *(unsigned short*)(vtb0 + i * 4096 + woff[j]) =                  \
            (unsigned short)vg[i][j];                                    \
  }

  short8 vg[4];
  STAGE_K(0);
  VLOAD(0);
  VWRITE(0);
  __syncthreads();   // publish Ks(0)+Vt(0)

  int nkt = 2 * qt + 2;
  for (int kt = 0; kt < nkt; ++kt) {
    int cur = kt & 1;
    bool pre = (kt + 1 < nkt);
    int kv0 = kt * 64;
    bool active = (kv0 <= qw0 + 31);
    if (pre) VLOAD(kt + 1);

    short4v pb[2][4];
    if (active) {
      f32x4 s[2][4];
      __builtin_amdgcn_s_setprio(1);
#pragma unroll
      for (int nb = 0; nb < 4; ++nb) {
        f32x4 a0 = {}, a1 = {};
#pragma unroll
        for (int kc = 0; kc < 4; ++kc) {
          int row = nb * 16 + l15;
          int c8 = (kc * 4 + l4) ^ l15;
          short8 kf = *(const short8*)(Ks + (row * 16 + c8) * 8);
          a0 = __builtin_amdgcn_mfma_f32_16x16x32_bf16(kf, qf[0][kc], a0, 0, 0, 0);
          a1 = __builtin_amdgcn_mfma_f32_16x16x32_bf16(kf, qf[1][kc], a1, 0, 0, 0);
        }
        s[0][nb] = a0;
        s[1][nb] = a1;
      }
      __builtin_amdgcn_s_setprio(0);
      bool diag = (kv0 + 63 > qw0);
      if (diag) {
#pragma unroll
        for (int qb = 0; qb < 2; ++qb) {
          int qq = qg + qb * 16;
#pragma unroll
          for (int nb = 0; nb < 4; ++nb)
#pragma unroll
            for (int r = 0; r < 4; ++r)
              if ((kv0 + nb * 16 + l4 * 4 + r) > qq) s[qb][nb][r] = -1e30f;
        }
      }
#pragma unroll
      for (int qb = 0; qb < 2; ++qb) {
        float t = -INFINITY;
#pragma unroll
        for (int nb = 0; nb < 4; ++nb)
#pragma unroll
          for (int r = 0; r < 4; ++r) t = fmaxf(t, s[qb][nb][r]);
        t = fmaxf(t, __shfl_xor(t, 16));
        t = fmaxf(t, __shfl_xor(t, 32));
        if (t > m[qb] + 11.5f) {      // defer-max (exp2 domain)
          float al = EXP2F(m[qb] - t);
          m[qb] = t;
          ls[qb] *= al;
#pragma unroll
          for (int db = 0; db < 8; ++db)
#pragma unroll
            for (int r = 0; r < 4; ++r) o[qb][db][r] *= al;
        }
        float sum = 0.f;
#pragma unroll
        for (int nb = 0; nb < 4; ++nb) {
          float p0 = EXP2F(s[qb][nb][0] - m[qb]);
          float p1 = EXP2F(s[qb][nb][1] - m[qb]);
          float p2 = EXP2F(s[qb][nb][2] - m[qb]);
          float p3 = EXP2F(s[qb][nb][3] - m[qb]);
          sum += (p0 + p1) + (p2 + p3);
          pb[qb][nb] = pack4(p0, p1, p2, p3);
        }
        sum += __shfl_xor(sum, 16);
        sum += __shfl_xor(sum, 32);
        ls[qb] += sum;
      }
    }

    __syncthreads();
    if (pre) STAGE_K(kt + 1);

    if (active) {
      __builtin_amdgcn_s_setprio(1);
#pragma unroll
      for (int db = 0; db < 8; ++db) {
        short4v vf[4];
#pragma unroll
        for (int nb = 0; nb < 4; ++nb) {
          int idx = (db * 16 + l15) * 64 +
                    (((nb * 2 + (l4 >> 1)) ^ (l15 & 7)) << 3) + ((l4 & 1) << 2);
          vf[nb] = *(const short4v*)(Vt[cur] + idx);
        }
#pragma unroll
        for (int qb = 0; qb < 2; ++qb)
#pragma unroll
          for (int nb = 0; nb < 4; ++nb)
            o[qb][db] = MFMA16(vf[nb], pb[qb][nb], o[qb][db]);
      }
      __builtin_amdgcn_s_setprio(0);
    }
    if (pre) VWRITE(1 - cur);
    __syncthreads();
  }

#pragma unroll
  for (int qb = 0; qb < 2; ++qb) {
    float invl = 1.f / ls[qb];
    unsigned short* orow = ows + (size_t)(b * T_ + qg + qb * 16) * DIM_ + h * HD_;
#pragma unroll
    for (int db = 0; db < 8; ++db) {
      short4v pk = pack4(o[qb][db][0] * invl, o[qb][db][1] * invl,
                         o[qb][db][2] * invl, o[qb][db][3] * invl);
      *(short4v*)(orow + db * 16 + l4 * 4) = pk;
    }
  }
#undef STAGE_K
#undef VLOAD
#undef VWRITE
}

// ---------------- launch ----------------
extern "C" void kernel_launch(void* const* d_in, const int* in_sizes, int n_in,
                              void* d_out, int out_size, void* d_ws, size_t ws_size,
                              hipStream_t stream) {
  (void)in_sizes; (void)n_in; (void)out_size; (void)ws_size;
  const float* x  = (const float*)d_in[0];
  const float* Wq = (const float*)d_in[1];
  const float* Wk = (const float*)d_in[2];
  const float* Wv = (const float*)d_in[3];
  const float* Wo = (const float*)d_in[4];
  float* out = (float*)d_out;
  char* ws = (char*)d_ws;
  // ws: q 32MB | kv 16MB | Wall(Wq^T|Wk^T|Wv^T) 12MB | Wot 8MB = 68MB
  unsigned short* q_ws  = (unsigned short*)(ws + 0);
  unsigned short* kv_ws = (unsigned short*)(ws + 33554432);
  unsigned short* Wall  = (unsigned short*)(ws + 50331648);
  unsigned short* Wot   = (unsigned short*)(ws + 62914560);
  unsigned short* xb = (unsigned short*)d_out;  // dead until final GEMM

  prep_kernel<<<18432, 256, 0, stream>>>(x, Wq, Wk, Wv, Wo, xb, Wall, Wot);

  gemm256_q<<<8 * (BT_ / 256), 512, 0, stream>>>(xb, Wall, q_ws);
  gemm_bt<<<dim3(KVS_ / 128, BT_ / 128), 256, 0, stream>>>(
      xb, Wall + (size_t)2048 * DIM_, kv_ws, BT_, KVS_, DIM_);

  rope_kernel<<<(B_ * T_ * (H_ + KVH_)) / 4, 256, 0, stream>>>(q_ws, kv_ws);

  attn_kernel<<<dim3(B_ * H_, T_ / 128), 256, 0, stream>>>(q_ws, kv_ws, q_ws);

  gemm256_out<<<8 * (BT_ / 256), 512, 0, stream>>>(q_ws, Wot, out);
}

// Round 20
// 342.775 us; speedup vs baseline: 1.0437x; 1.0437x over previous
//
#include <hip/hip_runtime.h>
#include <stdint.h>
#include <math.h>

#define DEV static __device__ __forceinline__

typedef __attribute__((ext_vector_type(8))) short short8;
typedef __attribute__((ext_vector_type(4))) short short4v;
typedef __attribute__((ext_vector_type(4))) float f32x4;

#define B_ 4
#define T_ 2048
#define H_ 16
#define KVH_ 4
#define HD_ 128
#define DIM_ 2048
#define KVD_ 512
#define BT_ (B_ * T_)
#define KVS_ 1024   // fused KV row stride (K cols 0..511, V cols 512..1023)

DEV float bf2f(unsigned short h) {
  union { uint32_t u; float f; } v; v.u = ((uint32_t)h) << 16; return v.f;
}
DEV unsigned short f2bf(float f) {
  uint32_t u = __builtin_bit_cast(uint32_t, f);
  u += 0x7fffu + ((u >> 16) & 1u);   // round-to-nearest-even
  return (unsigned short)(u >> 16);
}
DEV void gll16(const void* g, void* l) {
  __builtin_amdgcn_global_load_lds(
      (const __attribute__((address_space(1))) unsigned int*)g,
      (__attribute__((address_space(3))) unsigned int*)l, 16, 0, 0);
}

#if __has_builtin(__builtin_amdgcn_exp2f)
#define EXP2F(x) __builtin_amdgcn_exp2f(x)
#else
#define EXP2F(x) exp2f(x)
#endif

// pack 4 fp32 -> 4 bf16 (RNE) via v_cvt_pk_bf16_f32
DEV short4v pack4(float a, float b, float c, float d) {
  union { uint32_t u[2]; short4v s; } r;
  asm("v_cvt_pk_bf16_f32 %0, %1, %2" : "=v"(r.u[0]) : "v"(a), "v"(b));
  asm("v_cvt_pk_bf16_f32 %0, %1, %2" : "=v"(r.u[1]) : "v"(c), "v"(d));
  return r.s;
}

#if __has_builtin(__builtin_amdgcn_mfma_f32_16x16x16bf16_1k)
#define MFMA16(A, Bo, C) __builtin_amdgcn_mfma_f32_16x16x16bf16_1k((A), (Bo), (C), 0, 0, 0)
#else
DEV f32x4 mfma16_asm(short4v a, short4v b, f32x4 c) {
  asm volatile("v_mfma_f32_16x16x16_bf16 %0, %1, %2, %0" : "+v"(c) : "v"(a), "v"(b));
  return c;
}
#define MFMA16(A, Bo, C) mfma16_asm((A), (Bo), (C))
#endif

// compiler-level + scheduler-level fence, then HW barrier (no vmcnt drain)
DEV void block_bar() {
  __builtin_amdgcn_sched_barrier(0);
  asm volatile("" ::: "memory");
  __builtin_amdgcn_s_barrier();
  asm volatile("" ::: "memory");
  __builtin_amdgcn_sched_barrier(0);
}

// ---------------- prep: cvt x + weight transposes + rope cos/sin table ----------------
DEV void tr32(const float* __restrict__ W, unsigned short* __restrict__ Wt,
              int R, int C, int bx, int by, int tid) {
  __shared__ float t[32][33];
  int c0 = bx * 32, r0 = by * 32;
  int col = tid & 31;
  int rr = (tid >> 5) * 4;
#pragma unroll
  for (int i = 0; i < 4; ++i)
    t[rr + i][col] = W[(size_t)(r0 + rr + i) * C + c0 + col];
  __syncthreads();
#pragma unroll
  for (int i = 0; i < 4; ++i)
    Wt[(size_t)(c0 + rr + i) * R + r0 + col] = f2bf(t[col][rr + i]);
}

__global__ __launch_bounds__(256) void prep_kernel(
    const float* __restrict__ x, const float* __restrict__ Wq,
    const float* __restrict__ Wk, const float* __restrict__ Wv,
    const float* __restrict__ Wo, unsigned short* __restrict__ xb,
    unsigned short* __restrict__ Wall, unsigned short* __restrict__ Wot,
    float2* __restrict__ rtab) {
  int id = blockIdx.x, tid = threadIdx.x;
  if (id < 8192) {
    size_t idx = (size_t)id * 2048 + tid * 8;
    float4 a = *(const float4*)(x + idx);
    float4 b = *(const float4*)(x + idx + 4);
    short8 o;
    o[0] = (short)f2bf(a.x); o[1] = (short)f2bf(a.y);
    o[2] = (short)f2bf(a.z); o[3] = (short)f2bf(a.w);
    o[4] = (short)f2bf(b.x); o[5] = (short)f2bf(b.y);
    o[6] = (short)f2bf(b.z); o[7] = (short)f2bf(b.w);
    *(short8*)(xb + idx) = o;
  } else if (id < 12288) {
    int t = id - 8192;
    tr32(Wq, Wall, DIM_, DIM_, t & 63, t >> 6, tid);
  } else if (id < 13312) {
    int t = id - 12288;
    tr32(Wk, Wall + (size_t)2048 * DIM_, DIM_, KVD_, t & 15, t >> 4, tid);
  } else if (id < 14336) {
    int t = id - 13312;
    tr32(Wv, Wall + (size_t)2560 * DIM_, DIM_, KVD_, t & 15, t >> 4, tid);
  } else if (id < 18432) {
    int t = id - 14336;
    tr32(Wo, Wot, DIM_, DIM_, t & 63, t >> 6, tid);
  } else {
    // rope table: t in [0,2048), j in [0,64): (cos, sin) of t * 10000^{-j/64}
    int t = (id - 18432) * 4 + (tid >> 6);
    int j = tid & 63;
    float inv = __expf(-(float)j * 0.14391157f);  // ln(10000)/64
    float ang = (float)t * inv;
    rtab[t * 64 + j] = make_float2(cosf(ang), sinf(ang));
  }
}

// ---------------- RoPE in-place, KV only (bf16); one wave per head-row ----------------
__global__ __launch_bounds__(256) void rope_kv(unsigned short* kv) {
  int wid = blockIdx.x * 4 + (threadIdx.x >> 6);   // 0..32767
  int lane = threadIdx.x & 63;
  int bt = wid >> 2, g = wid & 3;
  unsigned short* ptr = kv + (size_t)bt * KVS_ + g * HD_;
  int t = bt & (T_ - 1);
  float inv = __expf(-(float)lane * 0.14391157f);  // ln(10000)/64
  float ang = (float)t * inv;
  float s = sinf(ang), c = cosf(ang);
  uint32_t zz = *(const uint32_t*)(ptr + lane * 2);
  float z1 = bf2f((unsigned short)(zz & 0xffff));
  float z2 = bf2f((unsigned short)(zz >> 16));
  unsigned short o1 = f2bf(z1 * c - z2 * s);
  unsigned short o2 = f2bf(z1 * s + z2 * c);
  ptr[lane] = o1;
  ptr[64 + lane] = o2;
}

// ---------------- GEMM 128² (m97 structure) — KV projection ----------------
__global__ __launch_bounds__(256) void gemm_bt(
    const unsigned short* __restrict__ A, const unsigned short* __restrict__ Bt,
    unsigned short* __restrict__ Cout, int M, int N, int K) {
  __shared__ unsigned short As[128 * 32];
  __shared__ unsigned short Bs[128 * 32];
  int m0 = blockIdx.y * 128, n0 = blockIdx.x * 128;
  int tid = threadIdx.x, w = tid >> 6, l = tid & 63;
  int wr = w >> 1, wc = w & 1;
  int l15 = l & 15, l4 = l >> 4;
  f32x4 acc[4][4] = {};
  for (int k0 = 0; k0 < K; k0 += 32) {
    __syncthreads();
#pragma unroll
    for (int i = 0; i < 2; ++i) {
      int u = i * 256 + w * 64 + l;
      int row = u >> 2, kc = u & 3;
      gll16(A + (size_t)(m0 + row) * K + k0 + kc * 8, As + (size_t)u * 8);
      gll16(Bt + (size_t)(n0 + row) * K + k0 + kc * 8, Bs + (size_t)u * 8);
    }
    __syncthreads();
    short8 a[4], b[4];
#pragma unroll
    for (int mb = 0; mb < 4; ++mb)
      a[mb] = *(const short8*)(As + ((wr * 64 + mb * 16 + l15) * 4 + l4) * 8);
#pragma unroll
    for (int nb = 0; nb < 4; ++nb)
      b[nb] = *(const short8*)(Bs + ((wc * 64 + nb * 16 + l15) * 4 + l4) * 8);
#pragma unroll
    for (int mb = 0; mb < 4; ++mb)
#pragma unroll
      for (int nb = 0; nb < 4; ++nb)
        acc[mb][nb] =
            __builtin_amdgcn_mfma_f32_16x16x32_bf16(a[mb], b[nb], acc[mb][nb], 0, 0, 0);
  }
#pragma unroll
  for (int mb = 0; mb < 4; ++mb)
#pragma unroll
    for (int nb = 0; nb < 4; ++nb)
#pragma unroll
      for (int r = 0; r < 4; ++r) {
        size_t off = (size_t)(m0 + wr * 64 + mb * 16 + l4 * 4 + r) * N +
                     n0 + wc * 64 + nb * 16 + l15;
        Cout[off] = f2bf(acc[mb][nb][r]);
      }
}

// ---------------- GEMM 256² deep-pipeline core (R13-proven two-phase) ----------------
#define GEMM256_BODY(A_, Bt_, K_, NX_)                                        \
  __shared__ unsigned short As[4][256 * 32];                                  \
  __shared__ unsigned short Bs[4][256 * 32];                                  \
  int tid = threadIdx.x, w = tid >> 6, l = tid & 63;                          \
  int wm = w >> 2, wn = w & 3;                                                \
  int l15 = l & 15, l4 = l >> 4;                                              \
  int cpx = (int)gridDim.x >> 3;                                              \
  int id = ((int)blockIdx.x & 7) * cpx + ((int)blockIdx.x >> 3);              \
  int bx = id % (NX_), by = id / (NX_);                                       \
  int m0 = by * 256, n0 = bx * 256;                                           \
  int nt = (K_) >> 5;                                                         \
  int u0 = tid * 16;                                                          \
  int ba0 = u0 ^ (((u0 >> 7) & 3) << 4);                                      \
  int r0 = ba0 >> 6;                                                          \
  int c0 = (ba0 & 63) >> 1;                                                   \
  f32x4 acc[8][4] = {};                                                       \
  _Pragma("unroll") for (int tt = 0; tt < 3; ++tt) {                          \
    const unsigned short* a0 = (A_) + (size_t)(m0 + r0) * (K_) + tt * 32 + c0;\
    gll16(a0, &As[tt][tid * 8]);                                              \
    gll16(a0 + (size_t)128 * (K_), &As[tt][4096 + tid * 8]);                  \
    const unsigned short* b0 = (Bt_) + (size_t)(n0 + r0) * (K_) + tt * 32 + c0;\
    gll16(b0, &Bs[tt][tid * 8]);                                              \
    gll16(b0 + (size_t)128 * (K_), &Bs[tt][4096 + tid * 8]);                  \
  }                                                                           \
  asm volatile("s_waitcnt vmcnt(8)" ::: "memory");                            \
  block_bar();                                                                \
  _Pragma("unroll 4") for (int t = 0; t < nt; ++t) {                          \
    int buf = t & 3;                                                          \
    int pf = t + 3;                                                           \
    bool dopf = pf < nt;                                                      \
    int pbuf = pf & 3;                                                        \
    if (dopf) {                                                               \
      const unsigned short* a0 = (A_) + (size_t)(m0 + r0) * (K_) + pf * 32 + c0;\
      gll16(a0, &As[pbuf][tid * 8]);                                          \
      gll16(a0 + (size_t)128 * (K_), &As[pbuf][4096 + tid * 8]);              \
    }                                                                         \
    short8 bfr[4], afr[4];                                                    \
    _Pragma("unroll") for (int nf = 0; nf < 4; ++nf) {                        \
      int row = wn * 64 + nf * 16 + l15;                                      \
      bfr[nf] = *(const short8*)(&Bs[buf][row * 32 + ((l4 ^ ((row >> 1) & 3)) << 3)]);\
    }                                                                         \
    _Pragma("unroll") for (int mf = 0; mf < 4; ++mf) {                        \
      int row = wm * 128 + mf * 16 + l15;                                     \
      afr[mf] = *(const short8*)(&As[buf][row * 32 + ((l4 ^ ((row >> 1) & 3)) << 3)]);\
    }                                                                         \
    asm volatile("s_waitcnt lgkmcnt(0)" ::: "memory");                        \
    __builtin_amdgcn_sched_barrier(0);                                        \
    __builtin_amdgcn_s_setprio(1);                                            \
    _Pragma("unroll") for (int mf = 0; mf < 4; ++mf)                          \
      _Pragma("unroll") for (int nf = 0; nf < 4; ++nf)                        \
        acc[mf][nf] = __builtin_amdgcn_mfma_f32_16x16x32_bf16(afr[mf], bfr[nf], acc[mf][nf], 0, 0, 0);\
    __builtin_amdgcn_s_setprio(0);                                            \
    block_bar();                                                              \
    if (dopf) {                                                               \
      const unsigned short* b0 = (Bt_) + (size_t)(n0 + r0) * (K_) + pf * 32 + c0;\
      gll16(b0, &Bs[pbuf][tid * 8]);                                          \
      gll16(b0 + (size_t)128 * (K_), &Bs[pbuf][4096 + tid * 8]);              \
    }                                                                         \
    short8 afr2[4];                                                           \
    _Pragma("unroll") for (int mf = 0; mf < 4; ++mf) {                        \
      int row = wm * 128 + 64 + mf * 16 + l15;                                \
      afr2[mf] = *(const short8*)(&As[buf][row * 32 + ((l4 ^ ((row >> 1) & 3)) << 3)]);\
    }                                                                         \
    asm volatile("s_waitcnt lgkmcnt(0)" ::: "memory");                        \
    __builtin_amdgcn_sched_barrier(0);                                        \
    __builtin_amdgcn_s_setprio(1);                                            \
    _Pragma("unroll") for (int mf = 0; mf < 4; ++mf)                          \
      _Pragma("unroll") for (int nf = 0; nf < 4; ++nf)                        \
        acc[4 + mf][nf] = __builtin_amdgcn_mfma_f32_16x16x32_bf16(afr2[mf], bfr[nf], acc[4 + mf][nf], 0, 0, 0);\
    __builtin_amdgcn_s_setprio(0);                                            \
    asm volatile("s_waitcnt vmcnt(8)" ::: "memory");                          \
    block_bar();                                                              \
  }

// ---------------- Q projection (bf16 out, SCALEQ folded) ----------------
__global__ __launch_bounds__(512, 2) void gemm256_q(
    const unsigned short* __restrict__ A, const unsigned short* __restrict__ Bt,
    unsigned short* __restrict__ Cq) {
  GEMM256_BODY(A, Bt, DIM_, 8)
  const float qs = 0.12752940f;   // (1/sqrt(128))*log2(e) for exp2-domain attn
#pragma unroll
  for (int mf = 0; mf < 8; ++mf)
#pragma unroll
    for (int nf = 0; nf < 4; ++nf)
#pragma unroll
      for (int r = 0; r < 4; ++r) {
        size_t off = (size_t)(m0 + wm * 128 + mf * 16 + l4 * 4 + r) * DIM_ +
                     n0 + wn * 64 + nf * 16 + l15;
        Cq[off] = f2bf(acc[mf][nf][r] * qs);
      }
}

// ---------------- O projection: fp32 out ----------------
__global__ __launch_bounds__(512, 2) void gemm256_out(
    const unsigned short* __restrict__ A, const unsigned short* __restrict__ Bt,
    float* __restrict__ Cout) {
  GEMM256_BODY(A, Bt, DIM_, 8)
#pragma unroll
  for (int mf = 0; mf < 8; ++mf)
#pragma unroll
    for (int nf = 0; nf < 4; ++nf)
#pragma unroll
      for (int r = 0; r < 4; ++r) {
        size_t off = (size_t)(m0 + wm * 128 + mf * 16 + l4 * 4 + r) * DIM_ +
                     n0 + wn * 64 + nf * 16 + l15;
        Cout[off] = acc[mf][nf][r];
      }
}

// ---------------- Flash attention v9: v7 + in-register Q-rope from table ----------------
__global__ __launch_bounds__(256, 2) void attn_kernel(
    const unsigned short* qws, const unsigned short* __restrict__ kvws,
    const float2* __restrict__ rtab, unsigned short* ows) {
  int bh = blockIdx.x;
  int qt = 15 - (int)blockIdx.y;      // LPT: longest first
  int b = bh >> 4, h = bh & 15, g = h >> 2;
  int tid = threadIdx.x, w = tid >> 6, l = tid & 63;
  int l15 = l & 15, l4 = l >> 4;

  __shared__ unsigned short Ks[64 * 128];     // 16 KB single
  __shared__ unsigned short Vt[2][128 * 64];  // 32 KB double (V^T, swizzled)

  const unsigned short* kbase = kvws + (size_t)(b * T_) * KVS_ + g * HD_;
  const unsigned short* vbase = kbase + KVD_;   // V cols at +512

  int q0 = qt * 128;
  int qw0 = q0 + w * 32;              // wave's first q row
  int qg = qw0 + l15;                 // lane's q row (qb adds 16)

  // Q load + in-register rope. Lane's output slots p = kc*32+l4*8+i need
  // inputs [l4*16, +16) (cos/sin j=l4*8+i, kc 0/2) and [64+l4*16, +16)
  // (j=32+l4*8+i, kc 1/3). Scale was pre-folded (rope commutes with scalar).
  short8 qf[2][4];
#pragma unroll
  for (int qb = 0; qb < 2; ++qb) {
    int tq = qg + qb * 16;
    const unsigned short* qrow = qws + (size_t)(b * T_ + tq) * DIM_ + h * HD_;
    unsigned short va[16], vb[16];
    *(short8*)(va) = *(const short8*)(qrow + l4 * 16);
    *(short8*)(va + 8) = *(const short8*)(qrow + l4 * 16 + 8);
    *(short8*)(vb) = *(const short8*)(qrow + 64 + l4 * 16);
    *(short8*)(vb + 8) = *(const short8*)(qrow + 64 + l4 * 16 + 8);
    const float2* ta = rtab + tq * 64 + l4 * 8;
#pragma unroll
    for (int i = 0; i < 8; ++i) {
      float2 cza = ta[i];                  // j = l4*8 + i
      float z1 = bf2f(va[2 * i]), z2 = bf2f(va[2 * i + 1]);
      qf[qb][0][i] = (short)f2bf(z1 * cza.x - z2 * cza.y);
      qf[qb][2][i] = (short)f2bf(z1 * cza.y + z2 * cza.x);
      float2 czb = ta[32 + i];             // j = 32 + l4*8 + i
      float y1 = bf2f(vb[2 * i]), y2 = bf2f(vb[2 * i + 1]);
      qf[qb][1][i] = (short)f2bf(y1 * czb.x - y2 * czb.y);
      qf[qb][3][i] = (short)f2bf(y1 * czb.y + y2 * czb.x);
    }
  }

  unsigned woff[8];
#pragma unroll
  for (int j = 0; j < 8; ++j)
    woff[j] = (unsigned)(j * 128 + (((l >> 3) ^ j) << 4) + ((l & 7) << 1));

  f32x4 o[2][8] = {};
  float m[2], ls[2];
  m[0] = m[1] = -INFINITY;
  ls[0] = ls[1] = 0.f;

#define STAGE_K(kt_)                                                     \
  {                                                                      \
    const unsigned short* kb = kbase + (size_t)(kt_) * 64 * KVS_;        \
    _Pragma("unroll") for (int i = 0; i < 4; ++i) {                      \
      int u = (i * 4 + w) * 64 + l;                                      \
      int row = u >> 4, c = u & 15;                                      \
      int kc = c ^ (row & 15);                                           \
      gll16(kb + (size_t)row * KVS_ + kc * 8, Ks + (size_t)u * 8);       \
    }                                                                    \
  }
#define VLOAD(kt_)                                                       \
  {                                                                      \
    const unsigned short* vrow = vbase + (size_t)((kt_) * 64 + l) * KVS_;\
    _Pragma("unroll") for (int i = 0; i < 4; ++i)                        \
      vg[i] = *(const short8*)(vrow + (w + i * 4) * 8);                  \
  }
#define VWRITE(buf_)                                                     \
  {                                                                      \
    char* vtb0 = (char*)Vt[buf_] + w * 1024;                             \
    _Pragma("unroll") for (int i = 0; i < 4; ++i)                        \
      _Pragma("unroll") for (int j = 0; j < 8; ++j)                      \
        *(unsigned short*)(vtb0 + i * 4096 + woff[j]) =                  \
            (unsigned short)vg[i][j];                                    \
  }

  short8 vg[4];
  STAGE_K(0);
  VLOAD(0);
  VWRITE(0);
  __syncthreads();   // publish Ks(0)+Vt(0)

  int nkt = 2 * qt + 2;
  for (int kt = 0; kt < nkt; ++kt) {
    int cur = kt & 1;
    bool pre = (kt + 1 < nkt);
    int kv0 = kt * 64;
    bool active = (kv0 <= qw0 + 31);
    if (pre) VLOAD(kt + 1);

    short4v pb[2][4];
    if (active) {
      f32x4 s[2][4];
      __builtin_amdgcn_s_setprio(1);
#pragma unroll
      for (int nb = 0; nb < 4; ++nb) {
        f32x4 a0 = {}, a1 = {};
#pragma unroll
        for (int kc = 0; kc < 4; ++kc) {
          int row = nb * 16 + l15;
          int c8 = (kc * 4 + l4) ^ l15;
          short8 kf = *(const short8*)(Ks + (row * 16 + c8) * 8);
          a0 = __builtin_amdgcn_mfma_f32_16x16x32_bf16(kf, qf[0][kc], a0, 0, 0, 0);
          a1 = __builtin_amdgcn_mfma_f32_16x16x32_bf16(kf, qf[1][kc], a1, 0, 0, 0);
        }
        s[0][nb] = a0;
        s[1][nb] = a1;
      }
      __builtin_amdgcn_s_setprio(0);
      bool diag = (kv0 + 63 > qw0);
      if (diag) {
#pragma unroll
        for (int qb = 0; qb < 2; ++qb) {
          int qq = qg + qb * 16;
#pragma unroll
          for (int nb = 0; nb < 4; ++nb)
#pragma unroll
            for (int r = 0; r < 4; ++r)
              if ((kv0 + nb * 16 + l4 * 4 + r) > qq) s[qb][nb][r] = -1e30f;
        }
      }
#pragma unroll
      for (int qb = 0; qb < 2; ++qb) {
        float t = -INFINITY;
#pragma unroll
        for (int nb = 0; nb < 4; ++nb)
#pragma unroll
          for (int r = 0; r < 4; ++r) t = fmaxf(t, s[qb][nb][r]);
        t = fmaxf(t, __shfl_xor(t, 16));
        t = fmaxf(t, __shfl_xor(t, 32));
        if (t > m[qb] + 11.5f) {      // defer-max (exp2 domain)
          float al = EXP2F(m[qb] - t);
          m[qb] = t;
          ls[qb] *= al;
#pragma unroll
          for (int db = 0; db < 8; ++db)
#pragma unroll
            for (int r = 0; r < 4; ++r) o[qb][db][r] *= al;
        }
        float sum = 0.f;
#pragma unroll
        for (int nb = 0; nb < 4; ++nb) {
          float p0 = EXP2F(s[qb][nb][0] - m[qb]);
          float p1 = EXP2F(s[qb][nb][1] - m[qb]);
          float p2 = EXP2F(s[qb][nb][2] - m[qb]);
          float p3 = EXP2F(s[qb][nb][3] - m[qb]);
          sum += (p0 + p1) + (p2 + p3);
          pb[qb][nb] = pack4(p0, p1, p2, p3);
        }
        sum += __shfl_xor(sum, 16);
        sum += __shfl_xor(sum, 32);
        ls[qb] += sum;
      }
    }

    __syncthreads();
    if (pre) STAGE_K(kt + 1);

    if (active) {
      __builtin_amdgcn_s_setprio(1);
#pragma unroll
      for (int db = 0; db < 8; ++db) {
        short4v vf[4];
#pragma unroll
        for (int nb = 0; nb < 4; ++nb) {
          int idx = (db * 16 + l15) * 64 +
                    (((nb * 2 + (l4 >> 1)) ^ (l15 & 7)) << 3) + ((l4 & 1) << 2);
          vf[nb] = *(const short4v*)(Vt[cur] + idx);
        }
#pragma unroll
        for (int qb = 0; qb < 2; ++qb)
#pragma unroll
          for (int nb = 0; nb < 4; ++nb)
            o[qb][db] = MFMA16(vf[nb], pb[qb][nb], o[qb][db]);
      }
      __builtin_amdgcn_s_setprio(0);
    }
    if (pre) VWRITE(1 - cur);
    __syncthreads();
  }

#pragma unroll
  for (int qb = 0; qb < 2; ++qb) {
    float invl = 1.f / ls[qb];
    unsigned short* orow = ows + (size_t)(b * T_ + qg + qb * 16) * DIM_ + h * HD_;
#pragma unroll
    for (int db = 0; db < 8; ++db) {
      short4v pk = pack4(o[qb][db][0] * invl, o[qb][db][1] * invl,
                         o[qb][db][2] * invl, o[qb][db][3] * invl);
      *(short4v*)(orow + db * 16 + l4 * 4) = pk;
    }
  }
#undef STAGE_K
#undef VLOAD
#undef VWRITE
}

// ---------------- launch ----------------
extern "C" void kernel_launch(void* const* d_in, const int* in_sizes, int n_in,
                              void* d_out, int out_size, void* d_ws, size_t ws_size,
                              hipStream_t stream) {
  (void)in_sizes; (void)n_in; (void)out_size; (void)ws_size;
  const float* x  = (const float*)d_in[0];
  const float* Wq = (const float*)d_in[1];
  const float* Wk = (const float*)d_in[2];
  const float* Wv = (const float*)d_in[3];
  const float* Wo = (const float*)d_in[4];
  float* out = (float*)d_out;
  char* ws = (char*)d_ws;
  // ws: q 32MB | kv 16MB | Wall(Wq^T|Wk^T|Wv^T) 12MB | Wot 8MB = 68MB
  unsigned short* q_ws  = (unsigned short*)(ws + 0);
  unsigned short* kv_ws = (unsigned short*)(ws + 33554432);
  unsigned short* Wall  = (unsigned short*)(ws + 50331648);
  unsigned short* Wot   = (unsigned short*)(ws + 62914560);
  // d_out dead space: xb [0,32MB), rope table [32MB, 33MB)
  unsigned short* xb = (unsigned short*)d_out;
  float2* rtab = (float2*)((char*)d_out + 33554432);

  prep_kernel<<<18944, 256, 0, stream>>>(x, Wq, Wk, Wv, Wo, xb, Wall, Wot, rtab);

  gemm256_q<<<8 * (BT_ / 256), 512, 0, stream>>>(xb, Wall, q_ws);
  gemm_bt<<<dim3(KVS_ / 128, BT_ / 128), 256, 0, stream>>>(
      xb, Wall + (size_t)2048 * DIM_, kv_ws, BT_, KVS_, DIM_);

  rope_kv<<<8192, 256, 0, stream>>>(kv_ws);

  attn_kernel<<<dim3(B_ * H_, T_ / 128), 256, 0, stream>>>(q_ws, kv_ws, rtab, q_ws);

  gemm256_out<<<8 * (BT_ / 256), 512, 0, stream>>>(q_ws, Wot, out);
}